// Round 13
// baseline (182.274 us; speedup 1.0000x reference)
//
#include <hip/hip_runtime.h>
#include <stdint.h>

#define NCAT  919
#define KDIM  400
#define NDIM  100
#define BK    32
#define NSTEP 13                 // ceil(400/32); step 12 has 16 valid k
#define KPAD  408                // bf16; row = 816 B (16B-aligned b128; read banks 2-way free)
#define NROWS 100                // n=6 fragment row-clamps; cols 100..111 never stored
#define NTHR  256                // 4 waves/block; 2 blocks/CU = 2 waves/SIMD

typedef float  f32x4  __attribute__((ext_vector_type(4)));
typedef __bf16 bf16x8 __attribute__((ext_vector_type(8)));
typedef __bf16 bf16x2 __attribute__((ext_vector_type(2)));

// EXACT waves-per-EU bound (r12 lesson): __launch_bounds__(256,2) is only a
// MINIMUM -> compiler's occupancy heuristic rounded to 4 waves/EU, capped
// VGPR at 128, and spilled ~100 regs to scratch (VGPR_Count=128, latency-
// bound everything). min=max=2 pins the 256-VGPR tier: ~240 live, no spill.
__global__ void __launch_bounds__(NTHR)
__attribute__((amdgpu_waves_per_eu(2, 2)))
cat_dense(const float* __restrict__ in, const float* __restrict__ wt,
          const float* __restrict__ bias, float* __restrict__ out)
{
  __shared__ __bf16 wlds[NROWS * KPAD];      // 81600 B; x2 blocks = 163200 <= 163840

  // Bijective XCD-aware swizzle (m204): 919 = 7*115 + 114. Consecutive categories
  // share an XCD L2 -> partial 128B output lines merge before writeback.
  const int ob   = blockIdx.x;
  const int xcd  = ob & 7;
  const int bidx = ob >> 3;
  const int c    = (xcd < 7 ? xcd * 115 : 805 + (xcd - 7) * 114) + bidx;

  const int tid  = threadIdx.x;
  const int lane = tid & 63;
  const int wave = tid >> 6;
  const int rl   = lane & 15;                // fragment row (A) / col (B/D)
  const int kg   = (lane >> 4) * 8;          // fragment k offset

  const size_t rstride = (size_t)NCAT * KDIM;
  // Each wave owns 64 batch rows = 4 m-tiles of 16.
  const float* gA[4];
  #pragma unroll
  for (int mt = 0; mt < 4; ++mt)
    gA[mt] = in + (size_t)c * KDIM + (size_t)(wave * 64 + mt * 16 + rl) * rstride;
  const float* gW = wt + (size_t)c * (KDIM * NDIM);

  // 3 A-prefetch slots (96 VGPR), depth 3: LOADA(t+3) issued AFTER cvt(t)
  // reads slot t%3 == (t+3)%3 (source order enforces the WAR; r3's bug was
  // issuing the overwrite BEFORE the cvt).
  f32x4 areg[3][4][2];

#define LOADA(T) do {                                                      \
    const int kb_ = (T) * BK + kg;                                         \
    const int s_  = (T) % 3;                                               \
    if (kb_ + 8 <= KDIM) {   /* per-lane K-tail mask (step 12, kg>=16) */  \
      _Pragma("unroll")                                                    \
      for (int mt_ = 0; mt_ < 4; ++mt_) {                                  \
        areg[s_][mt_][0] = *(const f32x4*)(gA[mt_] + kb_);                 \
        areg[s_][mt_][1] = *(const f32x4*)(gA[mt_] + kb_ + 4);             \
      }                                                                    \
    } else {                                                               \
      _Pragma("unroll")                                                    \
      for (int mt_ = 0; mt_ < 4; ++mt_) {                                  \
        areg[s_][mt_][0] = f32x4{0,0,0,0};                                 \
        areg[s_][mt_][1] = f32x4{0,0,0,0};                                 \
      }                                                                    \
    }                                                                      \
  } while (0)

  // ---- prologue: 3 A-steps in flight; they land during W staging ----
  LOADA(0); LOADA(1); LOADA(2);

  // ---- stage full W_c -> LDS (transposed, bf16), ONCE; single barrier.
  // nq-sweep mapping (coalesced 400B global runs; r10 proved kp-sweep loses
  // more on global coalescing than it gains on LDS write banks). 4 groups of
  // 5 iters: w0/w1 live-pressure 40 VGPR; group chains hidden by the
  // co-resident block's compute (the point of 2 blocks/CU).
  #pragma unroll
  for (int g = 0; g < 4; ++g) {
    f32x4 w0[5], w1[5];
    #pragma unroll
    for (int i = 0; i < 5; ++i) {
      const int pc = tid + (g * 5 + i) * NTHR;     // pc = kp*25 + nq
      if (pc < 5000) {
        const int kp = pc / 25;
        const int nq = pc - kp * 25;
        const float* p = gW + (size_t)(2 * kp) * NDIM + nq * 4;
        w0[i] = *(const f32x4*)p;
        w1[i] = *(const f32x4*)(p + NDIM);
      }
    }
    #pragma unroll
    for (int i = 0; i < 5; ++i) {
      const int pc = tid + (g * 5 + i) * NTHR;
      if (pc < 5000) {
        const int kp = pc / 25;
        const int nq = pc - kp * 25;
        #pragma unroll
        for (int j = 0; j < 4; ++j) {
          bf16x2 pk = { (__bf16)w0[i][j], (__bf16)w1[i][j] };
          *(bf16x2*)&wlds[(nq * 4 + j) * KPAD + 2 * kp] = pk;
        }
      }
    }
  }
  // Full __syncthreads(): real fence semantics (round-4 lesson).
  __syncthreads();

  f32x4 acc[4][7];
  #pragma unroll
  for (int m = 0; m < 4; ++m)
    #pragma unroll
    for (int n = 0; n < 7; ++n) acc[m][n] = f32x4{0, 0, 0, 0};

  // ---- main loop: ZERO barriers; W read-only in LDS; A streams via registers ----
  #pragma unroll
  for (int t = 0; t < NSTEP; ++t) {
    const int pp = t % 3;
    bf16x8 a[4];
    #pragma unroll
    for (int mt = 0; mt < 4; ++mt) {
      #pragma unroll
      for (int j = 0; j < 4; ++j) {          // vmcnt wait for A(t) lands here
        a[mt][j]     = (__bf16)areg[pp][mt][0][j];
        a[mt][4 + j] = (__bf16)areg[pp][mt][1][j];
      }
    }
    if (t + 3 < NSTEP) LOADA(t + 3);         // same slot as pp, issued AFTER cvt

    // K-clamp: lanes that clamp (t=12, kg>=16) have A==0 -> finite B suffices.
    const int kb2  = t * BK + kg;
    const int koff = (kb2 <= KDIM - 8) ? kb2 : (KDIM - 8);
    #pragma unroll
    for (int n = 0; n < 7; ++n) {
      // n=6 row-clamp: cols 96..99 (rl<4) get true rows; cols>=100 never
      // stored; clamped lanes read identical addresses -> LDS broadcast.
      const int brow = n * 16 + (n == 6 ? (rl & 3) : rl);
      bf16x8 b = *(const bf16x8*)&wlds[brow * KPAD + koff];
      #pragma unroll
      for (int mt = 0; mt < 4; ++mt)
        acc[mt][n] = __builtin_amdgcn_mfma_f32_16x16x32_bf16(a[mt], b, acc[mt][n], 0, 0, 0);
    }
  }

  // ---- epilogue: C/D map (16x16 family): col = lane&15, row = (lane>>4)*4 + reg ----
  const float* gB = bias + (size_t)c * NDIM;
  float* gO = out + (size_t)c * NDIM;
  #pragma unroll
  for (int n = 0; n < 7; ++n) {
    const int col = n * 16 + rl;
    if (col < NDIM) {
      const float bv = gB[col];               // L2/L3-hot (367 KB total bias)
      #pragma unroll
      for (int mt = 0; mt < 4; ++mt) {
        const int r0 = wave * 64 + mt * 16 + (lane >> 4) * 4;
        #pragma unroll
        for (int j = 0; j < 4; ++j) {
          gO[(size_t)(r0 + j) * ((size_t)NCAT * NDIM) + col] = acc[mt][n][j] + bv;
        }
      }
    }
  }
}

extern "C" void kernel_launch(void* const* d_in, const int* in_sizes, int n_in,
                              void* d_out, int out_size, void* d_ws, size_t ws_size,
                              hipStream_t stream) {
  const float* in   = (const float*)d_in[0];
  const float* wt   = (const float*)d_in[1];
  const float* bias = (const float*)d_in[2];
  float* o          = (float*)d_out;
  cat_dense<<<dim3(NCAT), dim3(NTHR), 0, stream>>>(in, wt, bias, o);
}

// Round 14
// 144.402 us; speedup vs baseline: 1.2623x; 1.2623x over previous
//
#include <hip/hip_runtime.h>
#include <stdint.h>

#define NCAT  919
#define KDIM  400
#define NDIM  100
#define BK    32
#define NSTEP 13                 // ceil(400/32); step 12 has 16 valid k
#define KPAD  408                // bf16; row = 816 B (16B-aligned b128; read banks 2-way free)
#define NROWS 100                // n=6 fragment row-clamps; cols 100..111 never stored
                                 // LDS = 100*408*2 = 81600 B

typedef float  f32x4  __attribute__((ext_vector_type(4)));
typedef __bf16 bf16x8 __attribute__((ext_vector_type(8)));
typedef __bf16 bf16x2 __attribute__((ext_vector_type(2)));

__global__ void __launch_bounds__(512, 2)
cat_dense(const float* __restrict__ in, const float* __restrict__ wt,
          const float* __restrict__ bias, float* __restrict__ out)
{
  __shared__ __bf16 wlds[NROWS * KPAD];

  // Bijective XCD-aware swizzle (m204): 919 = 7*115 + 114. Consecutive categories
  // share an XCD L2 -> partial 128B output lines merge before writeback.
  const int ob   = blockIdx.x;
  const int xcd  = ob & 7;
  const int bidx = ob >> 3;
  const int c    = (xcd < 7 ? xcd * 115 : 805 + (xcd - 7) * 114) + bidx;

  const int tid  = threadIdx.x;
  const int lane = tid & 63;
  const int wave = tid >> 6;
  const int rl   = lane & 15;                // fragment row (A) / col (B/D)
  const int kg   = (lane >> 4) * 8;          // fragment k offset

  const size_t rstride = (size_t)NCAT * KDIM;
  const float* gA0 = in + (size_t)c * KDIM + (size_t)(wave * 32 + rl) * rstride;
  const float* gA1 = gA0 + (size_t)16 * rstride;
  const float* gW  = wt + (size_t)c * (KDIM * NDIM);

  // 6 A-prefetch slots (96 VGPR). Bursts of two steps (256B/row page runs,
  // r9-proven) at t=0,2,4; singles at t=8 (A10,A11: AFTER barrier-2) and t=9.
  // Slot T%6: always consumed >=2 steps before rewrite (verified schedule).
  f32x4 areg[6][2][2];

#define LOADA(T) do {                                                      \
    const int kb_ = (T) * BK + kg;                                         \
    if (kb_ + 8 <= KDIM) {   /* per-lane K-tail mask (step 12, kg>=16) */  \
      areg[(T) % 6][0][0] = *(const f32x4*)(gA0 + kb_);                    \
      areg[(T) % 6][0][1] = *(const f32x4*)(gA0 + kb_ + 4);                \
      areg[(T) % 6][1][0] = *(const f32x4*)(gA1 + kb_);                    \
      areg[(T) % 6][1][1] = *(const f32x4*)(gA1 + kb_ + 4);                \
    } else {                                                               \
      areg[(T) % 6][0][0] = f32x4{0,0,0,0};                                \
      areg[(T) % 6][0][1] = f32x4{0,0,0,0};                                \
      areg[(T) % 6][1][0] = f32x4{0,0,0,0};                                \
      areg[(T) % 6][1][1] = f32x4{0,0,0,0};                                \
    }                                                                      \
  } while (0)

  // ---- prologue: 4 A-steps + bias in flight; they land during W staging ----
  LOADA(0); LOADA(1); LOADA(2); LOADA(3);

  // Bias hoisted: kills the epilogue load->add->store latency chain.
  const float* gB = bias + (size_t)c * NDIM;
  float bv[7];
  #pragma unroll
  for (int n = 0; n < 7; ++n) {
    const int col = n * 16 + rl;
    bv[n] = (col < NDIM) ? gB[col] : 0.f;
  }

  // ---- W stage half 1: kp < 128 (k < 256), nq-SWEEP mapping (r9-proven:
  // consecutive lanes sweep nq -> 400B coalesced global runs). Load-all-
  // then-write-all so the HBM round-trips overlap instead of chaining.
  f32x4 wa0[7], wa1[7];
  #pragma unroll
  for (int i = 0; i < 7; ++i) {
    const int pc = tid + i * 512;              // pc = kp*25 + nq, kp<128
    if (pc < 3200) {
      const int kp = pc / 25;
      const int nq = pc - kp * 25;
      const float* p = gW + (size_t)(2 * kp) * NDIM + nq * 4;
      wa0[i] = *(const f32x4*)p;
      wa1[i] = *(const f32x4*)(p + NDIM);
    }
  }
  #pragma unroll
  for (int i = 0; i < 7; ++i) {
    const int pc = tid + i * 512;
    if (pc < 3200) {
      const int kp = pc / 25;
      const int nq = pc - kp * 25;
      #pragma unroll
      for (int j = 0; j < 4; ++j) {
        bf16x2 pk = { (__bf16)wa0[i][j], (__bf16)wa1[i][j] };
        *(bf16x2*)&wlds[(nq * 4 + j) * KPAD + 2 * kp] = pk;
      }
    }
  }
  // Barrier 1: k<256 visible. __syncthreads = real fence (round-4 lesson).
  __syncthreads();

  // ---- W stage half 2: kp in [128,200) (k in [256,400)). ISSUE loads now;
  // they land under compute t=0..7. Only 8 f32x4 (32 VGPR) held live.
  f32x4 wb0[4], wb1[4];
  #pragma unroll
  for (int i = 0; i < 4; ++i) {
    const int pc = tid + i * 512;              // pc = (kp-128)*25 + nq
    if (pc < 1800) {
      const int kp = 128 + pc / 25;
      const int nq = pc - (kp - 128) * 25;
      const float* p = gW + (size_t)(2 * kp) * NDIM + nq * 4;
      wb0[i] = *(const f32x4*)p;
      wb1[i] = *(const f32x4*)(p + NDIM);
    }
  }
  // Pin program order: don't let the scheduler sink these to their t==7 use
  // (round-7 failure mode under register pressure).
  __builtin_amdgcn_sched_barrier(0);

  f32x4 acc[2][7];
  #pragma unroll
  for (int m = 0; m < 2; ++m)
    #pragma unroll
    for (int n = 0; n < 7; ++n) acc[m][n] = f32x4{0, 0, 0, 0};

  // ---- main loop: t=0..7 read k<256; write half-2 + barrier at end of t=7;
  // t=8..12 read k>=256. ----
  #pragma unroll
  for (int t = 0; t < NSTEP; ++t) {
    const int pp = t % 6;
    bf16x8 a0, a1;
    #pragma unroll
    for (int j = 0; j < 4; ++j) {              // vmcnt wait for A(t) lands here
      a0[j]     = (__bf16)areg[pp][0][0][j];
      a0[4 + j] = (__bf16)areg[pp][0][1][j];
      a1[j]     = (__bf16)areg[pp][1][0][j];
      a1[4 + j] = (__bf16)areg[pp][1][1][j];
    }
    // A-prefetch: 256B page bursts; t=8 issues come AFTER barrier-2 so the
    // mid-loop __syncthreads never drains a just-issued load (in-flight there:
    // A8,A9 issued at t=4 — long arrived).
    if (t == 0 || t == 2 || t == 4) { LOADA(t + 4); LOADA(t + 5); }
    if (t == 8)                     { LOADA(10);    LOADA(11);    }
    if (t == 9)                     { LOADA(12);                  }

    // K-clamp: lanes that clamp (t=12, kg>=16) have A==0 -> finite B suffices.
    const int kb2  = t * BK + kg;
    const int koff = (kb2 <= KDIM - 8) ? kb2 : (KDIM - 8);
    #pragma unroll
    for (int n = 0; n < 7; ++n) {
      // n=6 row-clamp: cols 96..99 (rl<4) get true rows; cols>=100 never
      // stored; clamped lanes read identical addresses -> LDS broadcast.
      const int brow = n * 16 + (n == 6 ? (rl & 3) : rl);
      bf16x8 b = *(const bf16x8*)&wlds[brow * KPAD + koff];
      acc[0][n] = __builtin_amdgcn_mfma_f32_16x16x32_bf16(a0, b, acc[0][n], 0, 0, 0);
      acc[1][n] = __builtin_amdgcn_mfma_f32_16x16x32_bf16(a1, b, acc[1][n], 0, 0, 0);
    }

    if (t == 7) {
      // Half-2 loads arrived during t=0..7; write + barrier 2.
      #pragma unroll
      for (int i = 0; i < 4; ++i) {
        const int pc = tid + i * 512;
        if (pc < 1800) {
          const int kp = 128 + pc / 25;
          const int nq = pc - (kp - 128) * 25;
          #pragma unroll
          for (int j = 0; j < 4; ++j) {
            bf16x2 pk = { (__bf16)wb0[i][j], (__bf16)wb1[i][j] };
            *(bf16x2*)&wlds[(nq * 4 + j) * KPAD + 2 * kp] = pk;
          }
        }
      }
      __syncthreads();
    }
  }

  // ---- epilogue: C/D map (16x16 family): col = lane&15, row = (lane>>4)*4 + reg ----
  float* gO = out + (size_t)c * NDIM;
  #pragma unroll
  for (int n = 0; n < 7; ++n) {
    const int col = n * 16 + rl;
    if (col < NDIM) {
      #pragma unroll
      for (int m = 0; m < 2; ++m) {
        const int r0 = wave * 32 + m * 16 + (lane >> 4) * 4;
        #pragma unroll
        for (int j = 0; j < 4; ++j) {
          gO[(size_t)(r0 + j) * ((size_t)NCAT * NDIM) + col] = acc[m][n][j] + bv[n];
        }
      }
    }
  }
}

extern "C" void kernel_launch(void* const* d_in, const int* in_sizes, int n_in,
                              void* d_out, int out_size, void* d_ws, size_t ws_size,
                              hipStream_t stream) {
  const float* in   = (const float*)d_in[0];
  const float* wt   = (const float*)d_in[1];
  const float* bias = (const float*)d_in[2];
  float* o          = (float*)d_out;
  cat_dense<<<dim3(NCAT), dim3(512), 0, stream>>>(in, wt, bias, o);
}